// Round 4
// baseline (508.515 us; speedup 1.0000x reference)
//
#include <hip/hip_runtime.h>

typedef __bf16 bf16;
typedef unsigned short u16;
typedef __bf16 bf16x8 __attribute__((ext_vector_type(8)));
typedef __bf16 bf16x4 __attribute__((ext_vector_type(4)));
typedef float f32x4 __attribute__((ext_vector_type(4)));

#define GLD16(g, l) __builtin_amdgcn_global_load_lds( \
    (const __attribute__((address_space(1))) void*)(g), \
    (__attribute__((address_space(3))) void*)(l), 16, 0, 0)

#define MFMA_BF16 __builtin_amdgcn_mfma_f32_16x16x32_bf16

#define FENCE() asm volatile("" ::: "memory")
#define BARRIER() do { FENCE(); __builtin_amdgcn_s_barrier(); FENCE(); } while (0)

// ---------------- f32 -> bf16 conversion (flat 1-D, exact grid) ----------------
struct CvtFlat { const float* s[9]; bf16* d[9]; int off[10]; };  // off in 4-elem groups

__global__ __launch_bounds__(256) void cvt_flat(CvtFlat a) {
  const int g = blockIdx.x * 256 + threadIdx.x;
  int seg = 0;
  #pragma unroll
  for (int i = 1; i < 9; ++i) seg += (g >= a.off[i]) ? 1 : 0;
  const int loc = (g - a.off[seg]) * 4;
  const f32x4 v = *(const f32x4*)(a.s[seg] + loc);
  bf16x4 o;
  #pragma unroll
  for (int j = 0; j < 4; ++j) o[j] = (bf16)v[j];
  *(bf16x4*)(a.d[seg] + loc) = o;
}

// ---------------- GEMM: 256x256 tile, 2-slot LDS, 2 blocks/CU ----------------
struct GemmDesc {
  const bf16* X;   // [8192,1024] bf16
  const bf16* W;   // [1024,1024] bf16 (row-major; used as W^T -> NT gemm)
  const float* B;  // bias [1024] f32
  const float* R;  // optional residual [8192,1024] f32
  bf16* Y;         // bf16 output (vt=0 row-major, vt=1 per-head transposed)
  int vt;
};
struct GemmArgs { GemmDesc d[6]; };

// One BK=32 K-slice. Body: {12 ds_read_b128 || stage slice s+1 -> 32 MFMA}
// compiler-scheduled (fine lgkmcnt); the MFMA window covers the staged loads'
// latency; vmcnt(0)+barrier at slice end (2-slot ring forces full drain, but
// 2 resident blocks/CU cover the stall - the gemm128 mechanism, bigger tile).
template <bool STAGE, bool FINAL>
__device__ __forceinline__ void do_slice(
    int sv, u16 (&As)[2][8192], u16 (&Bs)[2][8192], f32x4 (&acc)[8][4],
    const int (&offA)[8], const int (&offB)[4],
    const bf16* __restrict__ X, const bf16* __restrict__ W,
    const int (&aoff)[2], const int (&boff)[2], const int (&sdst)[2]) {
  const u16* Asl = &As[sv & 1][0];
  const u16* Bsl = &Bs[sv & 1][0];
  bf16x8 a[8], b[4];
  #pragma unroll
  for (int nt = 0; nt < 4; ++nt) b[nt] = *(const bf16x8*)&Bsl[offB[nt]];
  #pragma unroll
  for (int mt = 0; mt < 8; ++mt) a[mt] = *(const bf16x8*)&Asl[offA[mt]];
  if constexpr (STAGE) {
    const int k0 = (sv + 1) * 32;
    u16* Ad = &As[(sv + 1) & 1][0];
    u16* Bd = &Bs[(sv + 1) & 1][0];
    #pragma unroll
    for (int i = 0; i < 2; ++i) GLD16(X + aoff[i] + k0, Ad + sdst[i]);
    #pragma unroll
    for (int i = 0; i < 2; ++i) GLD16(W + boff[i] + k0, Bd + sdst[i]);
  }
  __builtin_amdgcn_s_setprio(1);
  #pragma unroll
  for (int mt = 0; mt < 8; ++mt)
    #pragma unroll
    for (int nt = 0; nt < 4; ++nt)
      acc[mt][nt] = MFMA_BF16(a[mt], b[nt], acc[mt][nt], 0, 0, 0);
  __builtin_amdgcn_s_setprio(0);
  if constexpr (!FINAL) {
    asm volatile("s_waitcnt vmcnt(0)" ::: "memory");
    BARRIER();
  }
}

// Y[8192,1024] = X @ W^T + B (+ R). 256x256 tile, 8 waves (2M x 4N), each wave
// owns a 128x64 sub-tile. 2-slot LDS double-buffer (64 KB -> 2 blocks/CU so
// cross-block wave overlap hides the per-slice drain), stage of slice s+1
// issued at top of slice s so in-block MFMAs also cover the load latency.
// Block remap: lin%8 == XCD; XCD c gets tiles [c*16, c*16+16) for L2 locality.
__global__ __launch_bounds__(512, 2) void gemm256(GemmArgs args) {
  const GemmDesc g = args.d[blockIdx.z];
  __shared__ u16 As[2][8192];  // 2 slots x [256 rows][32 k] bf16 = 32 KB
  __shared__ u16 Bs[2][8192];  // 32 KB
  const int tid = threadIdx.x;
  const int w = tid >> 6, lane = tid & 63;
  const int lq = lane >> 4, ll = lane & 15;
  const int wr = w >> 2, wc = w & 3;                 // wave 2x4 grid
  const int lin = blockIdx.x + (blockIdx.y << 3);    // [0,128)
  const int tile = (lin & 7) * 16 + (lin >> 3);      // XCD-chunked, bijective
  const int mtile = tile >> 2, ntile = tile & 3;
  const int m0 = mtile * 256, n0 = ntile * 256;
  f32x4 acc[8][4] = {};

  // per-thread loop-invariant ds_read offsets (u16 units), swizzled:
  // LDS dest linear (global_load_lds) + inverse-swizzled global source
  // chunk c = (s&3) ^ ((r>>1)&3); read side applies the same XOR.
  int offA[8], offB[4];
  #pragma unroll
  for (int mt = 0; mt < 8; ++mt) {
    const int am = wr * 128 + mt * 16 + ll;
    offA[mt] = (am * 4 + (lq ^ ((am >> 1) & 3))) * 8;
  }
  #pragma unroll
  for (int nt = 0; nt < 4; ++nt) {
    const int bn = wc * 64 + nt * 16 + ll;
    offB[nt] = (bn * 4 + (lq ^ ((bn >> 1) & 3))) * 8;
  }

  // per-thread loop-invariant staging offsets (global elem offset, LDS dest)
  int aoff[2], boff[2], sdst[2];
  #pragma unroll
  for (int i = 0; i < 2; ++i) {
    const int sb = i * 512 + w * 64;      // wave-uniform 16B-chunk base
    const int s = sb + lane;
    const int r = s >> 2, c = (s & 3) ^ ((r >> 1) & 3);
    aoff[i] = (m0 + r) * 1024 + c * 8;
    boff[i] = (n0 + r) * 1024 + c * 8;
    sdst[i] = sb * 8;
  }

  // prologue: stage slice 0 into slot 0
  #pragma unroll
  for (int i = 0; i < 2; ++i) GLD16(g.X + aoff[i], &As[0][sdst[i]]);
  #pragma unroll
  for (int i = 0; i < 2; ++i) GLD16(g.W + boff[i], &Bs[0][sdst[i]]);
  asm volatile("s_waitcnt vmcnt(0)" ::: "memory");
  BARRIER();

  // main loop: 32 slices of K=32; slice s stages slice s+1
  #pragma unroll 2
  for (int s = 0; s < 31; ++s)
    do_slice<true, false>(s, As, Bs, acc, offA, offB, g.X, g.W, aoff, boff, sdst);
  do_slice<false, true>(31, As, Bs, acc, offA, offB, g.X, g.W, aoff, boff, sdst);

  // epilogue: bias (+residual), store (optionally per-head transposed)
  float biasv[4];
  #pragma unroll
  for (int nt = 0; nt < 4; ++nt) biasv[nt] = g.B[n0 + wc * 64 + nt * 16 + ll];

  #pragma unroll
  for (int mt = 0; mt < 8; ++mt) {
    #pragma unroll
    for (int r = 0; r < 4; ++r) {
      const int m = m0 + wr * 128 + mt * 16 + lq * 4 + r;
      #pragma unroll
      for (int nt = 0; nt < 4; ++nt) {
        const int n = n0 + wc * 64 + nt * 16 + ll;
        float v = acc[mt][nt][r] + biasv[nt];
        if (g.R) v += g.R[m * 1024 + n];
        if (!g.vt) {
          g.Y[m * 1024 + n] = (bf16)v;
        } else {
          const int bb = m >> 10, tok = m & 1023;
          g.Y[(((bb << 4) + (n >> 6)) * 64 + (n & 63)) * 1024 + tok] = (bf16)v;
        }
      }
    }
  }
}

// ---------------- attention (S^T formulation, no online max) ----------------
struct AttnDesc { const bf16* Qp; const bf16* Kp; const bf16* Vt; const float* mask; bf16* ctx; };

__global__ __launch_bounds__(256, 4) void attn_kernel(AttnDesc A0, AttnDesc A1) {
  const AttnDesc A = blockIdx.z ? A1 : A0;
  __shared__ u16 Ks[128 * 64];   // K tile [kk][d], 16B-chunk XOR(row&7); Q staging first
  __shared__ u16 Vts[64 * 128];  // V^T tile [d][kk], 16B-chunk XOR(row&15)
  __shared__ u16 Pts[4 * 1024];  // per-wave P [32 q][32 kk], chunk XOR(row&3)
  const int tid = threadIdx.x;
  const int w = tid >> 6, lane = tid & 63;
  const int lq = lane >> 4, ll = lane & 15;
  // Block remap: lin%8 == f(bh) so the 8 q-tile blocks sharing one head's
  // K/V (256 KB) land on the same XCD's L2.
  const int lin = blockIdx.x + (blockIdx.y << 3);      // [0,1024)
  const int bh = (lin & 7) | ((lin >> 6) << 3);        // [0,128)
  const int q0 = ((lin >> 3) & 7) * 128;
  const int b = bh >> 4, h = bh & 15;
  const float* mrow = A.mask + b * 1024;

  #pragma unroll
  for (int i = 0; i < 4; ++i) {
    const int sb = w * 256 + i * 64;
    const int s = sb + lane;
    const int r = s >> 3, c = (s & 7) ^ (r & 7);
    GLD16(A.Qp + (b * 1024 + q0 + r) * 1024 + h * 64 + c * 8, &Ks[sb * 8]);
  }
  __syncthreads();
  bf16x8 bq[2][2];  // Q B-frags, k-loop invariant
  #pragma unroll
  for (int nt = 0; nt < 2; ++nt)
    #pragma unroll
    for (int kd = 0; kd < 2; ++kd) {
      const int row = w * 32 + nt * 16 + ll;
      const int c8 = kd * 4 + lq;
      bq[nt][kd] = *(const bf16x8*)&Ks[row * 64 + ((c8 ^ (row & 7)) << 3)];
    }
  __syncthreads();

  f32x4 oacc[4][2] = {};
  float rsum[2] = {0.f, 0.f};

  for (int kt = 0; kt < 8; ++kt) {
    const int kk0 = kt * 128;
    #pragma unroll
    for (int i = 0; i < 4; ++i) {
      const int sb = w * 256 + i * 64;
      const int s = sb + lane;
      { const int r = s >> 3, c = (s & 7) ^ (r & 7);
        GLD16(A.Kp + (b * 1024 + kk0 + r) * 1024 + h * 64 + c * 8, &Ks[sb * 8]); }
      { const int r = s >> 4, c = (s & 15) ^ (r & 15);
        GLD16(A.Vt + (bh * 64 + r) * 1024 + kk0 + c * 8, &Vts[sb * 8]); }
    }
    __syncthreads();

    #pragma unroll
    for (int qtr = 0; qtr < 4; ++qtr) {
      bf16x8 ak[2][2];
      #pragma unroll
      for (int mh = 0; mh < 2; ++mh) {
        const int row = qtr * 32 + mh * 16 + ll;
        #pragma unroll
        for (int kd = 0; kd < 2; ++kd) {
          const int c8 = kd * 4 + lq;
          ak[mh][kd] = *(const bf16x8*)&Ks[row * 64 + ((c8 ^ (row & 7)) << 3)];
        }
      }
      f32x4 sacc[2][2] = {};
      #pragma unroll
      for (int mh = 0; mh < 2; ++mh)
        #pragma unroll
        for (int nt = 0; nt < 2; ++nt)
          #pragma unroll
          for (int kd = 0; kd < 2; ++kd)
            sacc[mh][nt] = MFMA_BF16(ak[mh][kd], bq[nt][kd], sacc[mh][nt], 0, 0, 0);

      f32x4 mv[2];
      #pragma unroll
      for (int mh = 0; mh < 2; ++mh)
        mv[mh] = *(const f32x4*)&mrow[kk0 + qtr * 32 + mh * 16 + lq * 4];

      #pragma unroll
      for (int mh = 0; mh < 2; ++mh)
        #pragma unroll
        for (int nt = 0; nt < 2; ++nt) {
          bf16x4 pv;
          #pragma unroll
          for (int rr = 0; rr < 4; ++rr) {
            const float p = __expf(fmaf(sacc[mh][nt][rr], 0.125f, mv[mh][rr]));
            rsum[nt] += p;
            pv[rr] = (bf16)p;
          }
          const int row = nt * 16 + ll;
          const int gq = mh * 2 + (lq >> 1);
          *(bf16x4*)&Pts[w * 1024 + row * 32 + ((gq ^ (row & 3)) << 3) + (lq & 1) * 4] = pv;
        }

      bf16x8 bp[2];
      #pragma unroll
      for (int nt = 0; nt < 2; ++nt) {
        const int row = nt * 16 + ll;
        bp[nt] = *(const bf16x8*)&Pts[w * 1024 + row * 32 + ((lq ^ (row & 3)) << 3)];
      }
      #pragma unroll
      for (int mtd = 0; mtd < 4; ++mtd) {
        const int row = mtd * 16 + ll;
        const int c16 = (qtr * 4 + lq) ^ (row & 15);
        const bf16x8 av = *(const bf16x8*)&Vts[row * 128 + (c16 << 3)];
        oacc[mtd][0] = MFMA_BF16(av, bp[0], oacc[mtd][0], 0, 0, 0);
        oacc[mtd][1] = MFMA_BF16(av, bp[1], oacc[mtd][1], 0, 0, 0);
      }
    }
    __syncthreads();
  }

  #pragma unroll
  for (int nt = 0; nt < 2; ++nt) {
    rsum[nt] += __shfl_xor(rsum[nt], 16, 64);
    rsum[nt] += __shfl_xor(rsum[nt], 32, 64);
  }

  #pragma unroll
  for (int nt = 0; nt < 2; ++nt) {
    const float inv = 1.f / rsum[nt];
    const int tok = q0 + w * 32 + nt * 16 + ll;
    #pragma unroll
    for (int mtd = 0; mtd < 4; ++mtd) {
      bf16x4 ov;
      #pragma unroll
      for (int rr = 0; rr < 4; ++rr) ov[rr] = (bf16)(oacc[mtd][nt][rr] * inv);
      *(bf16x4*)&A.ctx[(size_t)(b * 1024 + tok) * 1024 + h * 64 + mtd * 16 + lq * 4] = ov;
    }
  }
}

// ---------------- LayerNorm: bf16 pre-LN in, f32 out ----------------
__global__ __launch_bounds__(256) void ln_kernel(const bf16* __restrict__ pre_c,
                                                 const bf16* __restrict__ pre_q,
                                                 const float* __restrict__ gamma,
                                                 const float* __restrict__ beta,
                                                 float* __restrict__ out) {
  const int row = blockIdx.x;  // 0..16383; first 8192 rows = output 0
  const bf16* src = (row < 8192) ? (pre_c + (size_t)row * 1024)
                                 : (pre_q + (size_t)(row - 8192) * 1024);
  float* dst = out + (size_t)row * 1024;
  const int t = threadIdx.x;
  const bf16x4 xv = *(const bf16x4*)(src + t * 4);
  float x[4]; float s = 0.f, ss = 0.f;
  #pragma unroll
  for (int i = 0; i < 4; ++i) { x[i] = (float)xv[i]; s += x[i]; ss += x[i] * x[i]; }
  #pragma unroll
  for (int off = 1; off < 64; off <<= 1) { s += __shfl_xor(s, off, 64); ss += __shfl_xor(ss, off, 64); }
  __shared__ float red[8];
  const int w = t >> 6, lane = t & 63;
  if (lane == 0) { red[w * 2] = s; red[w * 2 + 1] = ss; }
  __syncthreads();
  s  = red[0] + red[2] + red[4] + red[6];
  ss = red[1] + red[3] + red[5] + red[7];
  const float mu = s * (1.f / 1024.f);
  float var = ss * (1.f / 1024.f) - mu * mu;
  var = fmaxf(var, 0.f);
  const float rs = rsqrtf(var + 1e-12f);
  const f32x4 gv = *(const f32x4*)(gamma + t * 4);
  const f32x4 bv = *(const f32x4*)(beta + t * 4);
  f32x4 yv;
  #pragma unroll
  for (int i = 0; i < 4; ++i) yv[i] = gv[i] * (x[i] - mu) * rs + bv[i];
  *(f32x4*)(dst + t * 4) = yv;
}

extern "C" void kernel_launch(void* const* d_in, const int* in_sizes, int n_in,
                              void* d_out, int out_size, void* d_ws, size_t ws_size,
                              hipStream_t stream) {
  const float* enc    = (const float*)d_in[0];
  const float* dec    = (const float*)d_in[1];
  const float* mask_c = (const float*)d_in[2];
  const float* mask_q = (const float*)d_in[3];
  const float* Wq  = (const float*)d_in[4];  const float* bq  = (const float*)d_in[5];
  const float* Wk  = (const float*)d_in[6];  const float* bk  = (const float*)d_in[7];
  const float* Wv  = (const float*)d_in[8];  const float* bv  = (const float*)d_in[9];
  const float* Wqq = (const float*)d_in[10]; const float* bqq = (const float*)d_in[11];
  const float* Wqk = (const float*)d_in[12]; const float* bqk = (const float*)d_in[13];
  const float* Wqv = (const float*)d_in[14]; const float* bqv = (const float*)d_in[15];
  const float* Wo  = (const float*)d_in[16]; const float* bo  = (const float*)d_in[17];
  const float* gamma = (const float*)d_in[18];
  const float* beta  = (const float*)d_in[19];
  float* out = (float*)d_out;

  bf16* ws = (bf16*)d_ws;
  const size_t XSZ = (size_t)8192 * 1024;  // 8M elems
  const size_t WSZ = (size_t)1024 * 1024;  // 1M elems
  bf16* enc_b = ws;
  bf16* dec_b = enc_b + XSZ;
  bf16* Wb[7];
  for (int i = 0; i < 7; ++i) Wb[i] = dec_b + XSZ + i * WSZ;
  bf16* after_w = Wb[6] + WSZ;  // 23M elems in

  CvtFlat ca;
  ca.s[0] = enc; ca.d[0] = enc_b;
  ca.s[1] = dec; ca.d[1] = dec_b;
  const float* Wsrc[7] = {Wq, Wk, Wv, Wqq, Wqk, Wqv, Wo};
  for (int i = 0; i < 7; ++i) { ca.s[2 + i] = Wsrc[i]; ca.d[2 + i] = Wb[i]; }
  int running = 0;
  const int segn[9] = {(int)(XSZ / 4), (int)(XSZ / 4), (int)(WSZ / 4), (int)(WSZ / 4),
                       (int)(WSZ / 4), (int)(WSZ / 4), (int)(WSZ / 4), (int)(WSZ / 4), (int)(WSZ / 4)};
  for (int i = 0; i < 9; ++i) { ca.off[i] = running; running += segn[i]; }
  ca.off[9] = running;
  const int cvt_blocks = running / 256;  // 23552

  const size_t need_par = (size_t)(23 + 48) * 1024 * 1024 * 2;  // 142 MiB

  cvt_flat<<<dim3(cvt_blocks), 256, 0, stream>>>(ca);

  if (ws_size >= need_par) {
    // ---------- parallel path: both branches in flight ----------
    bf16* Qc  = after_w;        bf16* Kc  = Qc + XSZ;  bf16* Vtc = Kc + XSZ;
    bf16* Qq  = Vtc + XSZ;      bf16* Kq  = Qq + XSZ;  bf16* Vtq = Kq + XSZ;
    bf16* ctx_c = enc_b;        // enc_b/dec_b dead after proj
    bf16* ctx_q = dec_b;
    bf16* pre_c = Qc;           // Q dead after attn
    bf16* pre_q = Qq;

    GemmArgs pa = {};
    pa.d[0] = {dec_b, Wb[0], bq,  nullptr, Qc,  0};
    pa.d[1] = {enc_b, Wb[1], bk,  nullptr, Kc,  0};
    pa.d[2] = {enc_b, Wb[2], bv,  nullptr, Vtc, 1};
    pa.d[3] = {enc_b, Wb[3], bqq, nullptr, Qq,  0};
    pa.d[4] = {dec_b, Wb[4], bqk, nullptr, Kq,  0};
    pa.d[5] = {dec_b, Wb[5], bqv, nullptr, Vtq, 1};
    gemm256<<<dim3(8, 16, 6), 512, 0, stream>>>(pa);

    AttnDesc a0 = {Qc, Kc, Vtc, mask_c, ctx_c};
    AttnDesc a1 = {Qq, Kq, Vtq, mask_q, ctx_q};
    attn_kernel<<<dim3(8, 128, 2), 256, 0, stream>>>(a0, a1);

    GemmArgs oa = {};
    oa.d[0] = {ctx_c, Wb[6], bo, enc, pre_c, 0};
    oa.d[1] = {ctx_q, Wb[6], bo, enc, pre_q, 0};
    gemm256<<<dim3(8, 16, 2), 512, 0, stream>>>(oa);

    ln_kernel<<<dim3(16384), 256, 0, stream>>>(pre_c, pre_q, gamma, beta, out);
  } else {
    // ---------- sequential fallback (126 MiB) ----------
    bf16* Q  = after_w;  bf16* K = Q + XSZ;  bf16* Vt = K + XSZ;
    bf16* ctx_c = Vt + XSZ;
    bf16* ctx_q = ctx_c + XSZ;
    bf16* pre_c = Q;
    bf16* pre_q = K;

    GemmArgs pa = {};
    pa.d[0] = {dec_b, Wb[0], bq,  nullptr, Q,  0};
    pa.d[1] = {enc_b, Wb[1], bk,  nullptr, K,  0};
    pa.d[2] = {enc_b, Wb[2], bv,  nullptr, Vt, 1};
    gemm256<<<dim3(8, 16, 3), 512, 0, stream>>>(pa);

    AttnDesc a0 = {Q, K, Vt, mask_c, ctx_c};
    attn_kernel<<<dim3(8, 128, 1), 256, 0, stream>>>(a0, a0);

    GemmArgs pb = {};
    pb.d[0] = {enc_b, Wb[3], bqq, nullptr, Q,  0};
    pb.d[1] = {dec_b, Wb[4], bqk, nullptr, K,  0};
    pb.d[2] = {dec_b, Wb[5], bqv, nullptr, Vt, 1};
    gemm256<<<dim3(8, 16, 3), 512, 0, stream>>>(pb);

    AttnDesc a1 = {Q, K, Vt, mask_q, ctx_q};
    attn_kernel<<<dim3(8, 128, 1), 256, 0, stream>>>(a1, a1);

    GemmArgs oa = {};
    oa.d[0] = {ctx_c, Wb[6], bo, enc, pre_c, 0};
    oa.d[1] = {ctx_q, Wb[6], bo, enc, pre_q, 0};
    gemm256<<<dim3(8, 16, 2), 512, 0, stream>>>(oa);

    ln_kernel<<<dim3(16384), 256, 0, stream>>>(pre_c, pre_q, gamma, beta, out);
  }
}

// Round 5
// 470.640 us; speedup vs baseline: 1.0805x; 1.0805x over previous
//
#include <hip/hip_runtime.h>

typedef __bf16 bf16;
typedef unsigned short u16;
typedef __bf16 bf16x8 __attribute__((ext_vector_type(8)));
typedef __bf16 bf16x4 __attribute__((ext_vector_type(4)));
typedef float f32x4 __attribute__((ext_vector_type(4)));

#define GLD16(g, l) __builtin_amdgcn_global_load_lds( \
    (const __attribute__((address_space(1))) void*)(g), \
    (__attribute__((address_space(3))) void*)(l), 16, 0, 0)

#define MFMA_BF16 __builtin_amdgcn_mfma_f32_16x16x32_bf16

#define FENCE() asm volatile("" ::: "memory")
#define BARRIER() do { FENCE(); __builtin_amdgcn_s_barrier(); FENCE(); } while (0)

// ---------------- f32 -> bf16 conversion (flat 1-D, exact grid) ----------------
struct CvtFlat { const float* s[9]; bf16* d[9]; int off[10]; };  // off in 4-elem groups

__global__ __launch_bounds__(256) void cvt_flat(CvtFlat a) {
  const int g = blockIdx.x * 256 + threadIdx.x;
  int seg = 0;
  #pragma unroll
  for (int i = 1; i < 9; ++i) seg += (g >= a.off[i]) ? 1 : 0;
  const int loc = (g - a.off[seg]) * 4;
  const f32x4 v = *(const f32x4*)(a.s[seg] + loc);
  bf16x4 o;
  #pragma unroll
  for (int j = 0; j < 4; ++j) o[j] = (bf16)v[j];
  *(bf16x4*)(a.d[seg] + loc) = o;
}

// ---------------- GEMM (reverted to measured-best 128x128 structure) ----------------
struct GemmDesc {
  const bf16* X;   // [8192,1024] bf16
  const bf16* W;   // [1024,1024] bf16 (row-major; used as W^T -> NT gemm)
  const float* B;  // bias [1024] f32
  const float* R;  // optional residual [8192,1024] f32
  bf16* Y;         // bf16 output (vt=0 row-major, vt=1 per-head transposed)
  int vt;
};
struct GemmArgs { GemmDesc d[6]; };

// Y[8192,1024] = X @ W^T + B (+ R). 128x128 tile, BK=64, 4 waves x 64x64.
// Block remap: lin%8 == f(m-tile) so all 8 n-tiles sharing an X panel land on
// one XCD (round-robin XCD assignment) -> X panel hits L2 after first block.
// ~2.7 resident blocks/CU cover each other's vmcnt drains (m114 mechanism).
__global__ __launch_bounds__(256, 2) void gemm128(GemmArgs args) {
  const GemmDesc g = args.d[blockIdx.z];
  __shared__ u16 As[128 * 64];
  __shared__ u16 Bs[128 * 64];
  const int tid = threadIdx.x;
  const int w = tid >> 6, lane = tid & 63;
  const int lq = lane >> 4, ll = lane & 15;
  const int lin = blockIdx.x + (blockIdx.y << 3);      // [0,512)
  const int ntile = (lin >> 3) & 7;                    // n-tile [0,8)
  const int mtile = (lin & 7) | ((lin >> 6) << 3);     // m-tile [0,64)
  const int m0 = mtile * 128, n0 = ntile * 128;
  const int wm = (w >> 1) * 64, wn = (w & 1) * 64;
  f32x4 acc[4][4] = {};

  for (int k0 = 0; k0 < 1024; k0 += 64) {
    #pragma unroll
    for (int i = 0; i < 4; ++i) {
      const int sb = w * 256 + i * 64;
      const int s = sb + lane;
      const int r = s >> 3, c = (s & 7) ^ (r & 7);
      GLD16(g.X + (m0 + r) * 1024 + k0 + c * 8, &As[sb * 8]);
      GLD16(g.W + (n0 + r) * 1024 + k0 + c * 8, &Bs[sb * 8]);
    }
    __syncthreads();
    #pragma unroll
    for (int kk = 0; kk < 64; kk += 32) {
      const int cb = (kk >> 3) + lq;
      bf16x8 a[4], b[4];
      #pragma unroll
      for (int t = 0; t < 4; ++t) {
        const int m = wm + t * 16 + ll;
        a[t] = *(const bf16x8*)&As[m * 64 + ((cb ^ (m & 7)) << 3)];
        const int n = wn + t * 16 + ll;
        b[t] = *(const bf16x8*)&Bs[n * 64 + ((cb ^ (n & 7)) << 3)];
      }
      #pragma unroll
      for (int mt = 0; mt < 4; ++mt)
        #pragma unroll
        for (int nt = 0; nt < 4; ++nt)
          acc[mt][nt] = MFMA_BF16(a[mt], b[nt], acc[mt][nt], 0, 0, 0);
    }
    __syncthreads();
  }

  float biasv[4];
  #pragma unroll
  for (int nt = 0; nt < 4; ++nt) biasv[nt] = g.B[n0 + wn + nt * 16 + ll];

  #pragma unroll
  for (int mt = 0; mt < 4; ++mt) {
    #pragma unroll
    for (int r = 0; r < 4; ++r) {
      const int m = m0 + wm + mt * 16 + lq * 4 + r;
      #pragma unroll
      for (int nt = 0; nt < 4; ++nt) {
        const int n = n0 + wn + nt * 16 + ll;
        float v = acc[mt][nt][r] + biasv[nt];
        if (g.R) v += g.R[m * 1024 + n];
        if (!g.vt) {
          g.Y[m * 1024 + n] = (bf16)v;
        } else {
          const int bb = m >> 10, tok = m & 1023;
          g.Y[(((bb << 4) + (n >> 6)) * 64 + (n & 63)) * 1024 + tok] = (bf16)v;
        }
      }
    }
  }
}

// ---------------- attention (S^T formulation, KVBLK=64 double-buffered) ----------------
// Change vs baseline: K/V tiles halved to 64 kv and double-buffered in the SAME
// 40 KB LDS footprint (4 blocks/CU preserved). Tile kt+1's global_load_lds are
// issued at the top of iter kt and waited with counted vmcnt(8) + raw s_barrier
// (never a vmcnt(0) drain mid-loop), so the stage latency hides under compute.
// Mask loads are hoisted BEFORE the stage issue: vmcnt retires oldest-first, so
// the compiler's wait for the mask regs retires only the mask loads and keeps
// the next tile's stages in flight.
struct AttnDesc { const bf16* Qp; const bf16* Kp; const bf16* Vt; const float* mask; bf16* ctx; };

__global__ __launch_bounds__(256, 4) void attn_kernel(AttnDesc A0, AttnDesc A1) {
  const AttnDesc A = blockIdx.z ? A1 : A0;
  __shared__ u16 Ks[2 * 64 * 64];   // dbuf K [kv64][d64], chunk XOR(r&7); Q staging (128x64) first
  __shared__ u16 Vts[2 * 64 * 64];  // dbuf V^T [d64][kk64], chunk XOR(r&7)
  __shared__ u16 Pts[4 * 1024];     // per-wave P [32 q][32 kk], chunk XOR(row&3)
  const int tid = threadIdx.x;
  const int w = tid >> 6, lane = tid & 63;
  const int lq = lane >> 4, ll = lane & 15;
  // Block remap: lin%8 == f(bh) so the 8 q-tile blocks sharing one head's
  // K/V (256 KB) land on the same XCD's L2.
  const int lin = blockIdx.x + (blockIdx.y << 3);      // [0,1024)
  const int bh = (lin & 7) | ((lin >> 6) << 3);        // [0,128)
  const int q0 = ((lin >> 3) & 7) * 128;
  const int b = bh >> 4, h = bh & 15;
  const float* mrow = A.mask + b * 1024;

  // ---- Q stage into Ks[0..8192) (128 rows x 64 d), then to regs ----
  #pragma unroll
  for (int i = 0; i < 4; ++i) {
    const int sb = w * 256 + i * 64;
    const int s = sb + lane;
    const int r = s >> 3, c = (s & 7) ^ (r & 7);
    GLD16(A.Qp + (b * 1024 + q0 + r) * 1024 + h * 64 + c * 8, &Ks[sb * 8]);
  }
  __syncthreads();
  bf16x8 bq[2][2];  // Q B-frags, k-loop invariant
  #pragma unroll
  for (int nt = 0; nt < 2; ++nt)
    #pragma unroll
    for (int kd = 0; kd < 2; ++kd) {
      const int row = w * 32 + nt * 16 + ll;
      const int c8 = kd * 4 + lq;
      bq[nt][kd] = *(const bf16x8*)&Ks[row * 64 + ((c8 ^ (row & 7)) << 3)];
    }
  __syncthreads();

  auto stage_kv = [&](int kt) {
    const int kk0 = kt << 6;
    const int db = (kt & 1) << 12;   // u16 offset, 4096 per buffer
    #pragma unroll
    for (int i = 0; i < 2; ++i) {
      const int sb = i * 256 + w * 64;
      const int s = sb + lane;
      const int r = s >> 3, c = (s & 7) ^ (r & 7);
      GLD16(A.Kp + (b * 1024 + kk0 + r) * 1024 + h * 64 + c * 8, &Ks[db + sb * 8]);
      GLD16(A.Vt + ((bh << 6) + r) * 1024 + kk0 + c * 8, &Vts[db + sb * 8]);
    }
  };

  f32x4 oacc[4][2] = {};
  float rsum[2] = {0.f, 0.f};

  stage_kv(0);  // prologue: tile 0 -> buf 0 (4 loads in flight)

  for (int kt = 0; kt < 16; ++kt) {
    const int kk0 = kt << 6;
    const int db = (kt & 1) << 12;
    // mask regs for this tile, loaded BEFORE the next-tile stage issue
    f32x4 mvk[2][2];
    #pragma unroll
    for (int qtr = 0; qtr < 2; ++qtr)
      #pragma unroll
      for (int mh = 0; mh < 2; ++mh)
        mvk[qtr][mh] = *(const f32x4*)&mrow[kk0 + qtr * 32 + mh * 16 + lq * 4];
    FENCE();
    if (kt < 15) {
      stage_kv(kt + 1);                                 // 4 more loads -> buf^1
      asm volatile("s_waitcnt vmcnt(8)" ::: "memory");  // retire tile kt's 4 stages
    } else {
      asm volatile("s_waitcnt vmcnt(4)" ::: "memory");  // retire tile 15's stages
    }
    BARRIER();  // all waves' tile-kt stages visible

    #pragma unroll
    for (int qtr = 0; qtr < 2; ++qtr) {
      bf16x8 ak[2][2];
      #pragma unroll
      for (int mh = 0; mh < 2; ++mh) {
        const int row = qtr * 32 + mh * 16 + ll;
        #pragma unroll
        for (int kd = 0; kd < 2; ++kd) {
          const int c8 = kd * 4 + lq;
          ak[mh][kd] = *(const bf16x8*)&Ks[db + row * 64 + ((c8 ^ (row & 7)) << 3)];
        }
      }
      f32x4 sacc[2][2] = {};
      #pragma unroll
      for (int mh = 0; mh < 2; ++mh)
        #pragma unroll
        for (int nt = 0; nt < 2; ++nt)
          #pragma unroll
          for (int kd = 0; kd < 2; ++kd)
            sacc[mh][nt] = MFMA_BF16(ak[mh][kd], bq[nt][kd], sacc[mh][nt], 0, 0, 0);

      #pragma unroll
      for (int mh = 0; mh < 2; ++mh)
        #pragma unroll
        for (int nt = 0; nt < 2; ++nt) {
          bf16x4 pv;
          #pragma unroll
          for (int rr = 0; rr < 4; ++rr) {
            const float p = __expf(fmaf(sacc[mh][nt][rr], 0.125f, mvk[qtr][mh][rr]));
            rsum[nt] += p;
            pv[rr] = (bf16)p;
          }
          const int row = nt * 16 + ll;
          const int gq = mh * 2 + (lq >> 1);
          *(bf16x4*)&Pts[w * 1024 + row * 32 + ((gq ^ (row & 3)) << 3) + (lq & 1) * 4] = pv;
        }

      bf16x8 bp[2];
      #pragma unroll
      for (int nt = 0; nt < 2; ++nt) {
        const int row = nt * 16 + ll;
        bp[nt] = *(const bf16x8*)&Pts[w * 1024 + row * 32 + ((lq ^ (row & 3)) << 3)];
      }
      #pragma unroll
      for (int mtd = 0; mtd < 4; ++mtd) {
        const int row = mtd * 16 + ll;
        const int c8v = ((qtr << 2) + lq) ^ (row & 7);
        const bf16x8 av = *(const bf16x8*)&Vts[db + row * 64 + (c8v << 3)];
        oacc[mtd][0] = MFMA_BF16(av, bp[0], oacc[mtd][0], 0, 0, 0);
        oacc[mtd][1] = MFMA_BF16(av, bp[1], oacc[mtd][1], 0, 0, 0);
      }
    }
    BARRIER();  // tile-kt reads done before buf[kt&1] is restaged next iter
  }

  #pragma unroll
  for (int nt = 0; nt < 2; ++nt) {
    rsum[nt] += __shfl_xor(rsum[nt], 16, 64);
    rsum[nt] += __shfl_xor(rsum[nt], 32, 64);
  }

  #pragma unroll
  for (int nt = 0; nt < 2; ++nt) {
    const float inv = 1.f / rsum[nt];
    const int tok = q0 + w * 32 + nt * 16 + ll;
    #pragma unroll
    for (int mtd = 0; mtd < 4; ++mtd) {
      bf16x4 ov;
      #pragma unroll
      for (int rr = 0; rr < 4; ++rr) ov[rr] = (bf16)(oacc[mtd][nt][rr] * inv);
      *(bf16x4*)&A.ctx[(size_t)(b * 1024 + tok) * 1024 + h * 64 + mtd * 16 + lq * 4] = ov;
    }
  }
}

// ---------------- LayerNorm: bf16 pre-LN in, f32 out ----------------
__global__ __launch_bounds__(256) void ln_kernel(const bf16* __restrict__ pre_c,
                                                 const bf16* __restrict__ pre_q,
                                                 const float* __restrict__ gamma,
                                                 const float* __restrict__ beta,
                                                 float* __restrict__ out) {
  const int row = blockIdx.x;  // 0..16383; first 8192 rows = output 0
  const bf16* src = (row < 8192) ? (pre_c + (size_t)row * 1024)
                                 : (pre_q + (size_t)(row - 8192) * 1024);
  float* dst = out + (size_t)row * 1024;
  const int t = threadIdx.x;
  const bf16x4 xv = *(const bf16x4*)(src + t * 4);
  float x[4]; float s = 0.f, ss = 0.f;
  #pragma unroll
  for (int i = 0; i < 4; ++i) { x[i] = (float)xv[i]; s += x[i]; ss += x[i] * x[i]; }
  #pragma unroll
  for (int off = 1; off < 64; off <<= 1) { s += __shfl_xor(s, off, 64); ss += __shfl_xor(ss, off, 64); }
  __shared__ float red[8];
  const int w = t >> 6, lane = t & 63;
  if (lane == 0) { red[w * 2] = s; red[w * 2 + 1] = ss; }
  __syncthreads();
  s  = red[0] + red[2] + red[4] + red[6];
  ss = red[1] + red[3] + red[5] + red[7];
  const float mu = s * (1.f / 1024.f);
  float var = ss * (1.f / 1024.f) - mu * mu;
  var = fmaxf(var, 0.f);
  const float rs = rsqrtf(var + 1e-12f);
  const f32x4 gv = *(const f32x4*)(gamma + t * 4);
  const f32x4 bv = *(const f32x4*)(beta + t * 4);
  f32x4 yv;
  #pragma unroll
  for (int i = 0; i < 4; ++i) yv[i] = gv[i] * (x[i] - mu) * rs + bv[i];
  *(f32x4*)(dst + t * 4) = yv;
}

extern "C" void kernel_launch(void* const* d_in, const int* in_sizes, int n_in,
                              void* d_out, int out_size, void* d_ws, size_t ws_size,
                              hipStream_t stream) {
  const float* enc    = (const float*)d_in[0];
  const float* dec    = (const float*)d_in[1];
  const float* mask_c = (const float*)d_in[2];
  const float* mask_q = (const float*)d_in[3];
  const float* Wq  = (const float*)d_in[4];  const float* bq  = (const float*)d_in[5];
  const float* Wk  = (const float*)d_in[6];  const float* bk  = (const float*)d_in[7];
  const float* Wv  = (const float*)d_in[8];  const float* bv  = (const float*)d_in[9];
  const float* Wqq = (const float*)d_in[10]; const float* bqq = (const float*)d_in[11];
  const float* Wqk = (const float*)d_in[12]; const float* bqk = (const float*)d_in[13];
  const float* Wqv = (const float*)d_in[14]; const float* bqv = (const float*)d_in[15];
  const float* Wo  = (const float*)d_in[16]; const float* bo  = (const float*)d_in[17];
  const float* gamma = (const float*)d_in[18];
  const float* beta  = (const float*)d_in[19];
  float* out = (float*)d_out;

  bf16* ws = (bf16*)d_ws;
  const size_t XSZ = (size_t)8192 * 1024;  // 8M elems
  const size_t WSZ = (size_t)1024 * 1024;  // 1M elems
  bf16* enc_b = ws;
  bf16* dec_b = enc_b + XSZ;
  bf16* Wb[7];
  for (int i = 0; i < 7; ++i) Wb[i] = dec_b + XSZ + i * WSZ;
  bf16* after_w = Wb[6] + WSZ;  // 23M elems in

  CvtFlat ca;
  ca.s[0] = enc; ca.d[0] = enc_b;
  ca.s[1] = dec; ca.d[1] = dec_b;
  const float* Wsrc[7] = {Wq, Wk, Wv, Wqq, Wqk, Wqv, Wo};
  for (int i = 0; i < 7; ++i) { ca.s[2 + i] = Wsrc[i]; ca.d[2 + i] = Wb[i]; }
  int running = 0;
  const int segn[9] = {(int)(XSZ / 4), (int)(XSZ / 4), (int)(WSZ / 4), (int)(WSZ / 4),
                       (int)(WSZ / 4), (int)(WSZ / 4), (int)(WSZ / 4), (int)(WSZ / 4), (int)(WSZ / 4)};
  for (int i = 0; i < 9; ++i) { ca.off[i] = running; running += segn[i]; }
  ca.off[9] = running;
  const int cvt_blocks = running / 256;  // 23552

  const size_t need_par = (size_t)(23 + 48) * 1024 * 1024 * 2;  // 142 MiB

  cvt_flat<<<dim3(cvt_blocks), 256, 0, stream>>>(ca);

  if (ws_size >= need_par) {
    // ---------- parallel path: both branches in flight ----------
    bf16* Qc  = after_w;        bf16* Kc  = Qc + XSZ;  bf16* Vtc = Kc + XSZ;
    bf16* Qq  = Vtc + XSZ;      bf16* Kq  = Qq + XSZ;  bf16* Vtq = Kq + XSZ;
    bf16* ctx_c = enc_b;        // enc_b/dec_b dead after proj
    bf16* ctx_q = dec_b;
    bf16* pre_c = Qc;           // Q dead after attn
    bf16* pre_q = Qq;

    GemmArgs pa = {};
    pa.d[0] = {dec_b, Wb[0], bq,  nullptr, Qc,  0};
    pa.d[1] = {enc_b, Wb[1], bk,  nullptr, Kc,  0};
    pa.d[2] = {enc_b, Wb[2], bv,  nullptr, Vtc, 1};
    pa.d[3] = {enc_b, Wb[3], bqq, nullptr, Qq,  0};
    pa.d[4] = {dec_b, Wb[4], bqk, nullptr, Kq,  0};
    pa.d[5] = {dec_b, Wb[5], bqv, nullptr, Vtq, 1};
    gemm128<<<dim3(8, 64, 6), 256, 0, stream>>>(pa);

    AttnDesc a0 = {Qc, Kc, Vtc, mask_c, ctx_c};
    AttnDesc a1 = {Qq, Kq, Vtq, mask_q, ctx_q};
    attn_kernel<<<dim3(8, 128, 2), 256, 0, stream>>>(a0, a1);

    GemmArgs oa = {};
    oa.d[0] = {ctx_c, Wb[6], bo, enc, pre_c, 0};
    oa.d[1] = {ctx_q, Wb[6], bo, enc, pre_q, 0};
    gemm128<<<dim3(8, 64, 2), 256, 0, stream>>>(oa);

    ln_kernel<<<dim3(16384), 256, 0, stream>>>(pre_c, pre_q, gamma, beta, out);
  } else {
    // ---------- sequential fallback (126 MiB) ----------
    bf16* Q  = after_w;  bf16* K = Q + XSZ;  bf16* Vt = K + XSZ;
    bf16* ctx_c = Vt + XSZ;
    bf16* ctx_q = ctx_c + XSZ;
    bf16* pre_c = Q;
    bf16* pre_q = K;

    GemmArgs pa = {};
    pa.d[0] = {dec_b, Wb[0], bq,  nullptr, Q,  0};
    pa.d[1] = {enc_b, Wb[1], bk,  nullptr, K,  0};
    pa.d[2] = {enc_b, Wb[2], bv,  nullptr, Vt, 1};
    gemm128<<<dim3(8, 64, 3), 256, 0, stream>>>(pa);

    AttnDesc a0 = {Q, K, Vt, mask_c, ctx_c};
    attn_kernel<<<dim3(8, 128, 1), 256, 0, stream>>>(a0, a0);

    GemmArgs pb = {};
    pb.d[0] = {enc_b, Wb[3], bqq, nullptr, Q,  0};
    pb.d[1] = {dec_b, Wb[4], bqk, nullptr, K,  0};
    pb.d[2] = {dec_b, Wb[5], bqv, nullptr, Vt, 1};
    gemm128<<<dim3(8, 64, 3), 256, 0, stream>>>(pb);

    AttnDesc a1 = {Q, K, Vt, mask_q, ctx_q};
    attn_kernel<<<dim3(8, 128, 1), 256, 0, stream>>>(a1, a1);

    GemmArgs oa = {};
    oa.d[0] = {ctx_c, Wb[6], bo, enc, pre_c, 0};
    oa.d[1] = {ctx_q, Wb[6], bo, enc, pre_q, 0};
    gemm128<<<dim3(8, 64, 2), 256, 0, stream>>>(oa);

    ln_kernel<<<dim3(16384), 256, 0, stream>>>(pre_c, pre_q, gamma, beta, out);
  }
}